// Round 6
// baseline (2192.809 us; speedup 1.0000x reference)
//
#include <hip/hip_runtime.h>

// LightGCN: out = (x0 + A x0 + A^2 x0 + A^3 x0) / 4, COO 4M nnz, N=300k, D=64.
// R5: inter-layer activations bf16 (row=128B); R6: SGPR edge records.
// R7: hist/scan kernels folded into bucket pipeline (bhist/bscan/bucketB).
// R8: fp32 acc deleted; mean fused into final layer; layers 1-2 write-only.
// R9/R10: 16-deep gather batching -> NO effect (157.5 vs 158.8us, FETCH
//      308->373MB, dur invariant). spmm is NOT MLP/latency-bound; it is
//      VMEM-throughput-bound. Candidates: (A) per-wave-instruction TA cost
//      (~24cyc/gather measured, 2B/lane thin payload) or (B) per-CU MSHR
//      line-fill limit (~5.3 B/cyc/CU at ~600cyc L3 latency).
// R11: QUAD-EDGE gathers -- one wave VMEM serves 4 edges (16 lanes/edge x
//      uint2 = 128B/edge, 512B/instr). 4x fewer gather instructions, SAME
//      line set (discriminates A vs B: A -> ~2x faster, B -> unchanged).
//      Records remain SGPR-block loads; col/val per-lane select via cndmask
//      on grp=lane>>4; float4 accum per lane; end-of-row shfl_xor(16,32)
//      reduction; lanes 0-15 write the 128B output row.

#define NUSERS 200000
#define NITEMS 100000
#define NNODES 300000
#define DIM 64
#define NNZ_CNT 4000000

#define BSHIFT 10
#define BROWS  (1 << BSHIFT)                               // 1024 rows per bucket
#define NB     ((NNODES + BROWS - 1) >> BSHIFT)            // 293 buckets
#define EPB    8192                                        // edges per block (hist/A)

// ---------------- bf16 helpers (RNE) ----------------

__device__ __forceinline__ unsigned short f32_to_bf16(float f) {
    unsigned u = __float_as_uint(f);
    u += 0x7FFFu + ((u >> 16) & 1u);
    return (unsigned short)(u >> 16);
}
__device__ __forceinline__ float bf16_to_f32(unsigned short h) {
    return __uint_as_float(((unsigned)h) << 16);
}
// unpack a dword holding 2 bf16 (lo = even dim, hi = odd dim)
__device__ __forceinline__ float bf16_lo(unsigned u) {
    return __uint_as_float(u << 16);
}
__device__ __forceinline__ float bf16_hi(unsigned u) {
    return __uint_as_float(u & 0xFFFF0000u);
}

// ---------------- bucket totals: LDS hist, few global atomics ----------------

__global__ void __launch_bounds__(256) k_bhist(const int* __restrict__ rows,
                                               int* __restrict__ bcnt) {
    __shared__ int hist[NB];
    int t = threadIdx.x;
    int e0 = blockIdx.x * EPB;
    for (int i = t; i < NB; i += 256) hist[i] = 0;
    __syncthreads();
    for (int k = 0; k < EPB / 256; ++k) {
        int e = e0 + k * 256 + t;
        if (e < NNZ_CNT) atomicAdd(&hist[rows[e] >> BSHIFT], 1);
    }
    __syncthreads();
    for (int i = t; i < NB; i += 256) {
        int h = hist[i];
        if (h) atomicAdd(&bcnt[i], h);
    }
}

// 1 block, 512 threads: exclusive scan of bucket counts -> bases + cursors.
__global__ void k_bscan(const int* __restrict__ bcnt, int* __restrict__ bbase,
                        int* __restrict__ gcur) {
    int t = threadIdx.x;
    int v = (t < NB) ? bcnt[t] : 0;
    __shared__ int lds[512];
    lds[t] = v; __syncthreads();
    for (int d = 1; d < 512; d <<= 1) {
        int cur = lds[t];
        int add = (t >= d) ? lds[t - d] : 0;
        __syncthreads();
        lds[t] = cur + add;
        __syncthreads();
    }
    if (t < NB) {
        int e = lds[t] - v;          // exclusive
        bbase[t] = e;
        gcur[t]  = e;
    }
    if (t == 511) bbase[NB] = lds[511];   // == NNZ
}

// ---------------- Phase A: bucket staging (LDS-binned) ----------------

__global__ void __launch_bounds__(256) k_bucketA(
        const int* __restrict__ rows, const int* __restrict__ cols,
        const float* __restrict__ vals, int* __restrict__ gcursor,
        int2* __restrict__ staged) {
    __shared__ int hist[NB];
    __shared__ int lbase[NB];
    __shared__ int lcur[NB];
    int t = threadIdx.x;
    int e0 = blockIdx.x * EPB;
    for (int i = t; i < NB; i += 256) { hist[i] = 0; lcur[i] = 0; }
    __syncthreads();
    // pass 1: local histogram
    for (int k = 0; k < EPB / 256; ++k) {
        int e = e0 + k * 256 + t;
        if (e < NNZ_CNT) atomicAdd(&hist[rows[e] >> BSHIFT], 1);
    }
    __syncthreads();
    // reserve contiguous ranges per bucket
    for (int i = t; i < NB; i += 256) {
        int h = hist[i];
        lbase[i] = h ? atomicAdd(&gcursor[i], h) : 0;
    }
    __syncthreads();
    // pass 2: place edges
    for (int k = 0; k < EPB / 256; ++k) {
        int e = e0 + k * 256 + t;
        if (e >= NNZ_CNT) continue;
        int r = rows[e];
        int b = r >> BSHIFT;
        int p = lbase[b] + atomicAdd(&lcur[b], 1);
        int2 rec;
        rec.x = ((r & (BROWS - 1)) << 19) | cols[e];   // rel_row[10] | col[19]
        rec.y = __float_as_int(vals[e]);
        staged[p] = rec;
    }
}

// ---------------- Phase B: per-bucket count + scan + row sort ----------------

__global__ void __launch_bounds__(1024) k_bucketB(
        const int* __restrict__ bbase, const int2* __restrict__ staged,
        int2* __restrict__ packed, int* __restrict__ rowptr) {
    __shared__ int rcnt[BROWS];
    __shared__ int cur[BROWS];
    int b = blockIdx.x;
    int t = threadIdx.x;
    int r0 = b << BSHIFT;
    int r1 = min(r0 + BROWS, NNODES);
    int nrows = r1 - r0;
    rcnt[t] = 0;
    __syncthreads();
    int start = bbase[b];
    int end   = bbase[b + 1];
    // pass 1: per-row counts (load only .x of each record)
    const int* sx = (const int*)staged;
    for (int idx = start + t; idx < end; idx += 1024)
        atomicAdd(&rcnt[((unsigned)sx[idx << 1]) >> 19], 1);
    __syncthreads();
    int v = rcnt[t];
    // in-place inclusive scan (Hillis-Steele)
    for (int d = 1; d < 1024; d <<= 1) {
        int c = rcnt[t];
        int a = (t >= d) ? rcnt[t - d] : 0;
        __syncthreads();
        rcnt[t] = c + a;
        __syncthreads();
    }
    int excl = rcnt[t] - v;
    cur[t] = start + excl;
    if (t < nrows) rowptr[r0 + t] = start + excl;
    if (b == NB - 1 && t == 0) rowptr[NNODES] = end;   // == NNZ
    __syncthreads();
    // pass 2: scatter to row-major packed
    for (int idx = start + t; idx < end; idx += 1024) {
        int2 rec = staged[idx];
        int rel = ((unsigned)rec.x) >> 19;
        int col = rec.x & 0x7FFFF;
        int pos = atomicAdd(&cur[rel], 1);
        int2 out; out.x = col; out.y = rec.y;
        packed[pos] = out;
    }
}

// ---------------- x0 -> bf16 ----------------

__global__ void k_init0(const float* __restrict__ ue, const float* __restrict__ ie,
                        unsigned short* __restrict__ xb0) {
    int i = blockIdx.x * blockDim.x + threadIdx.x;      // float4 index
    const int total = NNODES * DIM / 4;
    if (i >= total) return;
    const int userEnd = NUSERS * DIM / 4;
    float4 v = (i < userEnd) ? ((const float4*)ue)[i]
                             : ((const float4*)ie)[i - userEnd];
    ushort4 h;
    h.x = f32_to_bf16(v.x); h.y = f32_to_bf16(v.y);
    h.z = f32_to_bf16(v.z); h.w = f32_to_bf16(v.w);
    ((ushort4*)xb0)[i] = h;
}

// ---------------- CSR SpMM: one wave/row, quad-edge gathers ----------------

// lane = 16*grp + sub. Edge quad [base+4q .. +3]: lane group grp handles edge
// base+4q+grp, loading uint2 (dims 4*sub..4*sub+3 of that source row); one
// wave VMEM instruction covers 4 edges (512B). Records come from 16-edge
// SGPR blocks (packed padded by 16 zero records -> no clamp; overshoot
// records are next rows' = prefetch). Out-of-row edges get v=0 via cndmask.
// End of row: shfl_xor(16,32) reduce; lanes 0-15 write the 128B row.
// FINAL=0: y = bf16(s)   FINAL=1: out = (x0 + x1 + x2 + s) * 0.25
template <int FINAL>
__global__ void __launch_bounds__(256) k_spmm(
        const int* __restrict__ rowptr, const int2* __restrict__ packed,
        const unsigned short* __restrict__ xin,
        unsigned short* __restrict__ y,
        const unsigned short* __restrict__ xprev,
        const float* __restrict__ ue, const float* __restrict__ ie,
        float* __restrict__ out) {
    int row  = blockIdx.x * (blockDim.x >> 6) + (threadIdx.x >> 6);
    int lane = threadIdx.x & 63;
    if (row >= NNODES) return;
    int grp = lane >> 4;          // which edge of the quad
    int sub = lane & 15;          // dim quad: dims 4*sub .. 4*sub+3
    int start = __builtin_amdgcn_readfirstlane(rowptr[row]);
    int end   = __builtin_amdgcn_readfirstlane(rowptr[row + 1]);
    const uint2* __restrict__ xq = (const uint2*)xin;    // 8B units, row stride 16
    float a0 = 0.f, a1 = 0.f, a2 = 0.f, a3 = 0.f;
    for (int base = start; base < end; base += 16) {
        int2 e[16];
        #pragma unroll
        for (int j = 0; j < 16; ++j) e[j] = packed[base + j];   // contiguous s_load block
        #pragma unroll
        for (int q = 0; q < 4; ++q) {
            int k = q * 4;
            // per-lane select of this group's edge (SGPR -> cndmask chain)
            int c01 = (grp & 1) ? e[k + 1].x : e[k + 0].x;
            int c23 = (grp & 1) ? e[k + 3].x : e[k + 2].x;
            int c   = (grp & 2) ? c23 : c01;
            float v01 = (grp & 1) ? __int_as_float(e[k + 1].y) : __int_as_float(e[k + 0].y);
            float v23 = (grp & 1) ? __int_as_float(e[k + 3].y) : __int_as_float(e[k + 2].y);
            float v   = (grp & 2) ? v23 : v01;
            v = (base + k + grp < end) ? v : 0.0f;               // tail mask
            uint2 d = xq[((size_t)c << 4) + sub];                // 4 edges / instr
            a0 += v * bf16_lo(d.x);
            a1 += v * bf16_hi(d.x);
            a2 += v * bf16_lo(d.y);
            a3 += v * bf16_hi(d.y);
        }
    }
    // reduce the 4 lane-groups (edges) onto group 0
    a0 += __shfl_xor(a0, 16); a0 += __shfl_xor(a0, 32);
    a1 += __shfl_xor(a1, 16); a1 += __shfl_xor(a1, 32);
    a2 += __shfl_xor(a2, 16); a2 += __shfl_xor(a2, 32);
    a3 += __shfl_xor(a3, 16); a3 += __shfl_xor(a3, 32);
    if (lane < 16) {
        size_t ro = (size_t)row * 16 + sub;                     // float4/ushort4 units
        if (FINAL) {
            float4 x0 = (row < NUSERS) ? ((const float4*)ue)[ro]
                                       : ((const float4*)ie)[ro - (size_t)NUSERS * 16];
            ushort4 h1 = ((const ushort4*)xprev)[ro];
            ushort4 h2 = ((const ushort4*)xin)[ro];
            float4 r;
            r.x = (x0.x + bf16_to_f32(h1.x) + bf16_to_f32(h2.x) + a0) * 0.25f;
            r.y = (x0.y + bf16_to_f32(h1.y) + bf16_to_f32(h2.y) + a1) * 0.25f;
            r.z = (x0.z + bf16_to_f32(h1.z) + bf16_to_f32(h2.z) + a2) * 0.25f;
            r.w = (x0.w + bf16_to_f32(h1.w) + bf16_to_f32(h2.w) + a3) * 0.25f;
            ((float4*)out)[ro] = r;
        } else {
            ushort4 h;
            h.x = f32_to_bf16(a0); h.y = f32_to_bf16(a1);
            h.z = f32_to_bf16(a2); h.w = f32_to_bf16(a3);
            ((ushort4*)y)[ro] = h;
        }
    }
}

// ---------------- launch ----------------

extern "C" void kernel_launch(void* const* d_in, const int* in_sizes, int n_in,
                              void* d_out, int out_size, void* d_ws, size_t ws_size,
                              hipStream_t stream) {
    const float* ue   = (const float*)d_in[0];
    const float* ie   = (const float*)d_in[1];
    const int*   rows = (const int*)d_in[2];
    const int*   cols = (const int*)d_in[3];
    const float* vals = (const float*)d_in[4];
    float* out = (float*)d_out;

    const size_t embN = (size_t)NNODES * DIM;            // 19.2M elements
    char* p = (char*)d_ws;
    unsigned short* xb0 = (unsigned short*)p;  p += embN * 2;                 // 38.4 MB
    unsigned short* xb1 = (unsigned short*)p;  p += embN * 2;                 // 38.4 MB
    unsigned short* xb2 = (unsigned short*)p;  p += embN * 2;                 // 38.4 MB
    int*   rowptr = (int*)p;              p += (size_t)(NNODES + 16) * 4;     // 1.2 MB
    int*   bcnt   = (int*)p;              p += 512 * 4;
    int*   bbase  = (int*)p;              p += 512 * 4;
    int*   gcur   = (int*)p;              p += 512 * 4;
    int2*  staged = (int2*)p;             p += (size_t)NNZ_CNT * 8;           // 32 MB
    int2*  packed = (int2*)p;             p += (size_t)(NNZ_CNT + 16) * 8;    // 32 MB + pad

    const int row_blocks  = (NNODES + 3) / 4;             // 4 waves/block
    const int edge_hblocks = (NNZ_CNT + EPB - 1) / EPB;   // 489
    const int vec_blocks = (NNODES * DIM / 4 + 255) / 256;

    // --- bucket totals + bases ---
    hipMemsetAsync(bcnt, 0, 512 * 4, stream);
    hipMemsetAsync(packed + NNZ_CNT, 0, 16 * sizeof(int2), stream);  // gather pad
    k_bhist<<<edge_hblocks, 256, 0, stream>>>(rows, bcnt);
    k_bscan<<<1, 512, 0, stream>>>(bcnt, bbase, gcur);

    // --- bucket sort: COO -> staged (bucket-major) -> packed (row-major) ---
    k_bucketA<<<edge_hblocks, 256, 0, stream>>>(rows, cols, vals, gcur, staged);
    k_bucketB<<<NB, 1024, 0, stream>>>(bbase, staged, packed, rowptr);

    // --- x0 -> bf16 ---
    k_init0<<<vec_blocks, 256, 0, stream>>>(ue, ie, xb0);

    // --- 3 layers; mean fused into the last (reads x0 fp32 + x1,x2 bf16) ---
    k_spmm<0><<<row_blocks, 256, 0, stream>>>(rowptr, packed, xb0, xb1,
                                              (const unsigned short*)nullptr, ue, ie, (float*)nullptr);
    k_spmm<0><<<row_blocks, 256, 0, stream>>>(rowptr, packed, xb1, xb2,
                                              (const unsigned short*)nullptr, ue, ie, (float*)nullptr);
    k_spmm<1><<<row_blocks, 256, 0, stream>>>(rowptr, packed, xb2, (unsigned short*)nullptr,
                                              xb1, ue, ie, out);
}